// Round 4
// baseline (120.223 us; speedup 1.0000x reference)
//
#include <hip/hip_runtime.h>
#include <math.h>

#define BATCH 4096
#define NNODES 10000
#define KCAND 100
#define F4_PER_BATCH 5000          // 10000 points * 2 floats / 4 per float4
#define F4_PER_BLOCK 10000         // 2 batches per block (contiguous rows)
#define NITER 40                   // ceil(10000 / 256)
#define PF 4                       // software-pipeline depth

typedef float f4 __attribute__((ext_vector_type(4)));

// 2048 blocks (all co-resident: 8 blocks/CU x 256 CU), 2 batches per block.
// Phase 1: threads [0,128) gather batch 2*blk, [128,256) gather 2*blk+1.
// Phase 2: one pipelined 40-iter stream over both contiguous rows.
__global__ __launch_bounds__(256) void fused2_normalize_kernel(
        const float* __restrict__ nodes,
        const int* __restrict__ cand,
        float* __restrict__ out) {
    const int blk = blockIdx.x;
    const int tid = threadIdx.x;
    const int wave = tid >> 6;
    const int lane = tid & 63;
    const int half = tid >> 7;                 // which batch this thread gathers
    const int b = blk * 2 + half;

    const float* nbase = nodes + (size_t)(blk * 2) * (NNODES * 2);
    const f4* src = reinterpret_cast<const f4*>(nbase);
    f4* dst = reinterpret_cast<f4*>(out + (size_t)(blk * 2) * (NNODES * 2));

    // ---- prefetch first PF streaming tiles (independent of gather chase) ----
    f4 buf[PF];
    #pragma unroll
    for (int j = 0; j < PF; ++j) {
        buf[j] = src[tid + j * 256];           // max idx 1023 < 10000
    }

    // ---- candidate gather: branchless 2-level chase ----
    const int c = tid & 127;
    const int cidx = c < KCAND ? c : (KCAND - 1);
    const int id = cand[(size_t)b * KCAND + cidx];
    const bool valid = (c < KCAND) && (id != -1);
    const int safe = valid ? id : 0;
    const float2 p = *reinterpret_cast<const float2*>(
        nodes + (size_t)b * (NNODES * 2) + (size_t)safe * 2);

    float xmin = valid ? p.x :  INFINITY;
    float xmax = valid ? p.x : -INFINITY;
    float ymin = valid ? p.y :  INFINITY;
    float ymax = valid ? p.y : -INFINITY;
    float any  = valid ? 1.0f : 0.0f;

    #pragma unroll
    for (int off = 32; off > 0; off >>= 1) {
        xmin = fminf(xmin, __shfl_xor(xmin, off, 64));
        xmax = fmaxf(xmax, __shfl_xor(xmax, off, 64));
        ymin = fminf(ymin, __shfl_xor(ymin, off, 64));
        ymax = fmaxf(ymax, __shfl_xor(ymax, off, 64));
        any  = fmaxf(any,  __shfl_xor(any,  off, 64));
    }

    // per-wave partials; waves 0,1 -> batch0, waves 2,3 -> batch1
    __shared__ float sred[5][4];
    if (lane == 0) {
        sred[0][wave] = xmin; sred[1][wave] = xmax;
        sred[2][wave] = ymin; sred[3][wave] = ymax;
        sred[4][wave] = any;
    }
    __syncthreads();

    // every thread computes params for BOTH batches (needed in the joint loop)
    float r0, bx0, by0, r1, bx1, by1;
    {
        const float x0n = fminf(sred[0][0], sred[0][1]);
        const float x0x = fmaxf(sred[1][0], sred[1][1]);
        const float y0n = fminf(sred[2][0], sred[2][1]);
        const float y0x = fmaxf(sred[3][0], sred[3][1]);
        const bool ok0 = fmaxf(sred[4][0], sred[4][1]) != 0.0f;
        r0 = 1.0f / fmaxf(fmaxf(x0x - x0n, y0x - y0n), 1e-6f);
        bx0 = -r0 * x0n; by0 = -r0 * y0n;
        // passthrough fold: inputs are in [0,1), clamp(v,0,1)==v there
        if (!ok0) { r0 = 1.0f; bx0 = 0.0f; by0 = 0.0f; }

        const float x1n = fminf(sred[0][2], sred[0][3]);
        const float x1x = fmaxf(sred[1][2], sred[1][3]);
        const float y1n = fminf(sred[2][2], sred[2][3]);
        const float y1x = fmaxf(sred[3][2], sred[3][3]);
        const bool ok1 = fmaxf(sred[4][2], sred[4][3]) != 0.0f;
        r1 = 1.0f / fmaxf(fmaxf(x1x - x1n, y1x - y1n), 1e-6f);
        bx1 = -r1 * x1n; by1 = -r1 * y1n;
        if (!ok1) { r1 = 1.0f; bx1 = 0.0f; by1 = 0.0f; }
    }

    // ---- pipelined streaming normalize over both rows ----
    #pragma unroll
    for (int it = 0; it < NITER; ++it) {
        const int i = tid + it * 256;
        const int ipf = i + PF * 256;
        f4 v = buf[it & (PF - 1)];
        if (ipf < F4_PER_BLOCK)
            buf[it & (PF - 1)] = src[ipf];
        if (i < F4_PER_BLOCK) {
            const bool hi = (i >= F4_PER_BATCH);
            const float r  = hi ? r1  : r0;
            const float bx = hi ? bx1 : bx0;
            const float by = hi ? by1 : by0;
            f4 o;
            o.x = fminf(fmaxf(fmaf(r, v.x, bx), 0.0f), 1.0f);
            o.y = fminf(fmaxf(fmaf(r, v.y, by), 0.0f), 1.0f);
            o.z = fminf(fmaxf(fmaf(r, v.z, bx), 0.0f), 1.0f);
            o.w = fminf(fmaxf(fmaf(r, v.w, by), 0.0f), 1.0f);
            __builtin_nontemporal_store(o, dst + i);
        }
    }
}

extern "C" void kernel_launch(void* const* d_in, const int* in_sizes, int n_in,
                              void* d_out, int out_size, void* d_ws, size_t ws_size,
                              hipStream_t stream) {
    const float* nodes = (const float*)d_in[0];
    const int* cand = (const int*)d_in[1];
    float* out = (float*)d_out;

    fused2_normalize_kernel<<<dim3(BATCH / 2), dim3(256), 0, stream>>>(nodes, cand, out);
}

// Round 5
// 112.330 us; speedup vs baseline: 1.0703x; 1.0703x over previous
//
#include <hip/hip_runtime.h>
#include <math.h>

#define BATCH 4096
#define NNODES 10000
#define KCAND 100
#define F4_PER_BATCH 5000          // 10000 points * 2 floats / 4 per float4
#define NITER 20                   // ceil(5000 / 256)
#define PF 8                       // software-pipeline depth (register tiles)

typedef float f4 __attribute__((ext_vector_type(4)));

// One block (256 threads = 4 waves) per batch, 4096 blocks, 8 blocks/CU.
// Prefetch first PF streaming tiles while the candidate gather chase is in
// flight, reduce bbox, then pipeline (load i+PF before process i).
__global__ __launch_bounds__(256, 8) void fused_normalize_kernel(
        const float* __restrict__ nodes,
        const int* __restrict__ cand,
        float* __restrict__ out) {
    const int b = blockIdx.x;
    const int tid = threadIdx.x;
    const int wave = tid >> 6;
    const int lane = tid & 63;

    const float* nb = nodes + (size_t)b * (NNODES * 2);
    const f4* src = reinterpret_cast<const f4*>(nb);
    f4* dst = reinterpret_cast<f4*>(out + (size_t)b * (NNODES * 2));

    // ---- prefetch first PF streaming tiles (independent of gather) ----
    f4 buf[PF];
    #pragma unroll
    for (int j = 0; j < PF; ++j) {
        buf[j] = __builtin_nontemporal_load(src + tid + j * 256);  // max 2047 < 5000
    }

    // ---- candidate gather: branchless 2-level chase ----
    const int cidx = tid < KCAND ? tid : (KCAND - 1);
    const int id = cand[(size_t)b * KCAND + cidx];
    const bool valid = (tid < KCAND) && (id != -1);
    const int safe = valid ? id : 0;
    const float2 p = *reinterpret_cast<const float2*>(nb + (size_t)safe * 2);

    float xmin = valid ? p.x :  INFINITY;
    float xmax = valid ? p.x : -INFINITY;
    float ymin = valid ? p.y :  INFINITY;
    float ymax = valid ? p.y : -INFINITY;
    float any  = valid ? 1.0f : 0.0f;

    #pragma unroll
    for (int off = 32; off > 0; off >>= 1) {
        xmin = fminf(xmin, __shfl_xor(xmin, off, 64));
        xmax = fmaxf(xmax, __shfl_xor(xmax, off, 64));
        ymin = fminf(ymin, __shfl_xor(ymin, off, 64));
        ymax = fmaxf(ymax, __shfl_xor(ymax, off, 64));
        any  = fmaxf(any,  __shfl_xor(any,  off, 64));
    }

    __shared__ float sred[5][4];
    if (lane == 0) {
        sred[0][wave] = xmin; sred[1][wave] = xmax;
        sred[2][wave] = ymin; sred[3][wave] = ymax;
        sred[4][wave] = any;
    }
    __syncthreads();
    xmin = fminf(fminf(sred[0][0], sred[0][1]), fminf(sred[0][2], sred[0][3]));
    xmax = fmaxf(fmaxf(sred[1][0], sred[1][1]), fmaxf(sred[1][2], sred[1][3]));
    ymin = fminf(fminf(sred[2][0], sred[2][1]), fminf(sred[2][2], sred[2][3]));
    ymax = fmaxf(fmaxf(sred[3][0], sred[3][1]), fmaxf(sred[3][2], sred[3][3]));
    any  = fmaxf(fmaxf(sred[4][0], sred[4][1]), fmaxf(sred[4][2], sred[4][3]));

    float r = 1.0f / fmaxf(fmaxf(xmax - xmin, ymax - ymin), 1e-6f);
    float bx = -r * xmin;              // out = clamp(fma(r, v, bx), 0, 1)
    float by = -r * ymin;
    // passthrough fold: inputs in [0,1) so clamp(v,0,1)==v -> identity params
    if (any == 0.0f) { r = 1.0f; bx = 0.0f; by = 0.0f; }

    // ---- pipelined streaming normalize ----
    #pragma unroll
    for (int it = 0; it < NITER; ++it) {
        const int i = tid + it * 256;
        const int ipf = i + PF * 256;
        f4 v = buf[it & (PF - 1)];
        if (ipf < F4_PER_BATCH)
            buf[it & (PF - 1)] = __builtin_nontemporal_load(src + ipf);
        if (i < F4_PER_BATCH) {
            f4 o;
            o.x = fminf(fmaxf(fmaf(r, v.x, bx), 0.0f), 1.0f);
            o.y = fminf(fmaxf(fmaf(r, v.y, by), 0.0f), 1.0f);
            o.z = fminf(fmaxf(fmaf(r, v.z, bx), 0.0f), 1.0f);
            o.w = fminf(fmaxf(fmaf(r, v.w, by), 0.0f), 1.0f);
            __builtin_nontemporal_store(o, dst + i);
        }
    }
}

extern "C" void kernel_launch(void* const* d_in, const int* in_sizes, int n_in,
                              void* d_out, int out_size, void* d_ws, size_t ws_size,
                              hipStream_t stream) {
    const float* nodes = (const float*)d_in[0];
    const int* cand = (const int*)d_in[1];
    float* out = (float*)d_out;

    fused_normalize_kernel<<<dim3(BATCH), dim3(256), 0, stream>>>(nodes, cand, out);
}